// Round 1
// 1109.321 us; speedup vs baseline: 1.1893x; 1.1893x over previous
//
#include <hip/hip_runtime.h>
#include <math.h>

#define BB 512
#define SS 16
#define HH 501
#define CC 7
#define KP 512                 // padded K (and padded rows per gate)
#define PBK (4*BB)             // floats per packed k-chunk = 2048
#define OFF_ENC (BB*SS*SS)

#define BUFSZ (132*PBK)
#define O_BUFIN 0
#define O_BUFH  BUFSZ          // retained for layout stability (unused)
#define O_ALIST (2*BUFSZ)
#define O_ELIST (O_ALIST + SS*BB)
#define O_CLS   (O_ELIST + SS*BB)
#define O_ZT    (O_CLS + SS*BB)      // zT hi+lo : 2 x 512*512 bf16 = 262144 floats
#define O_INT   (O_ZT  + 262144)     // inT hi+lo
#define O_HT    (O_INT + 262144)     // hT hi+lo
#define O_WLIN  (O_HT  + 262144)     // 32 slots * 8192 floats = 262144
#define O_WPOST (O_WLIN + 262144)    // 64 slots = 524288
#define O_WHH   (O_WPOST + 524288)   // 96 slots = 786432
#define O_WDOT  (O_WHH + 786432)     // 1 slot  = 8192

typedef __attribute__((ext_vector_type(8))) short bfrag;   // 8 bf16 = 4 VGPR
typedef __attribute__((ext_vector_type(4))) float ffrag;   // 4 f32 acc

__device__ __forceinline__ float sigm(float x) { return 1.f / (1.f + expf(-x)); }

__device__ __forceinline__ unsigned short f2bf(float x) {
    unsigned u = __float_as_uint(x);
    u = u + 0x7fffu + ((u >> 16) & 1u);          // RNE
    return (unsigned short)(u >> 16);
}
__device__ __forceinline__ float bf2f(unsigned short h) {
    return __uint_as_float(((unsigned)h) << 16);
}

// ---------- fragment-order weight preprocess (one-time) ---------------------
// A-frag element j of (slot, s, lane) = W[row = slot16 + (lane&15)][k = s*32 + (lane>>4)*8 + j]
// layout (ushort units): slot*16384 + (s*2+half)*512 + lane*8
__global__ __launch_bounds__(256) void k_wprep(
    const float* __restrict__ Wlin1, const float* __restrict__ Wgate,
    const float* __restrict__ Wmap,  const float* __restrict__ Whh,
    const float* __restrict__ Wedge, const float* __restrict__ Wvert,
    unsigned short* __restrict__ wlin, unsigned short* __restrict__ wpost,
    unsigned short* __restrict__ whhf, unsigned short* __restrict__ wdot)
{
    const int id = blockIdx.x * 256 + threadIdx.x;
    const int slot = id >> 10, rem = id & 1023, s = rem >> 6, lane = rem & 63;
    const int rloc = lane & 15;
    const int k0 = s * 32 + ((lane >> 4) << 3);
    const float* src; unsigned short* dst; int dslot; bool valid;
    if (slot < 32) {
        int row = slot * 16 + rloc; valid = row < HH;
        src = Wlin1 + (size_t)(valid ? row : 0) * HH; dst = wlin; dslot = slot;
    } else if (slot < 96) {
        int p = slot - 32, g = p >> 5, mt = p & 31;
        int row = mt * 16 + rloc; valid = row < HH;
        src = (g ? Wmap : Wgate) + (size_t)(valid ? row : 0) * HH; dst = wpost; dslot = p;
    } else if (slot < 192) {
        int p = slot - 96, g = p >> 5, mt = p & 31;
        int row = mt * 16 + rloc; valid = row < HH;
        src = Whh + (size_t)(g * HH + (valid ? row : 0)) * HH; dst = whhf; dslot = p;
    } else {
        int row = rloc; dst = wdot; dslot = 0;
        if (row < 2)      { src = Wedge + (size_t)row * HH; valid = true; }
        else if (row < 9) { src = Wvert + (size_t)(row - 2) * HH; valid = true; }
        else              { src = Wedge; valid = false; }
    }
    unsigned h[8], l[8];
#pragma unroll
    for (int j = 0; j < 8; ++j) {
        int k = k0 + j;
        float w = (valid && k < HH) ? src[k] : 0.f;
        unsigned short hb = f2bf(w);
        h[j] = hb; l[j] = f2bf(w - bf2f(hb));
    }
    size_t base = ((size_t)dslot * 32 + s * 2) * 512 + lane * 8;
    uint4 uh, ul;
    uh.x = h[0] | (h[1] << 16); uh.y = h[2] | (h[3] << 16);
    uh.z = h[4] | (h[5] << 16); uh.w = h[6] | (h[7] << 16);
    ul.x = l[0] | (l[1] << 16); ul.y = l[2] | (l[3] << 16);
    ul.z = l[4] | (l[5] << 16); ul.w = l[6] | (l[7] << 16);
    *(uint4*)&dst[base] = uh;
    *(uint4*)&dst[base + 512] = ul;
}

// ---------- prep: zT split, cls, zero dep region ----------------------------
__global__ __launch_bounds__(256) void k_prep2(
    const float* __restrict__ z, const float* __restrict__ xenc,
    unsigned short* __restrict__ zTh, unsigned short* __restrict__ zTl,
    int* __restrict__ cls, float* __restrict__ out)
{
    const int b = blockIdx.x, tid = threadIdx.x;
    if (b < 128) {
        const int id = b * 256 + tid;
        const int bb = id >> 6, kc = id & 63, k0 = kc * 8;
        unsigned h[8], l[8];
#pragma unroll
        for (int j = 0; j < 8; ++j) {
            int k = k0 + j;
            float w = (k < HH) ? z[(size_t)bb * HH + k] : 0.f;
            unsigned short hb = f2bf(w);
            h[j] = hb; l[j] = f2bf(w - bf2f(hb));
        }
        uint4 uh, ul;
        uh.x = h[0] | (h[1] << 16); uh.y = h[2] | (h[3] << 16);
        uh.z = h[4] | (h[5] << 16); uh.w = h[6] | (h[7] << 16);
        ul.x = l[0] | (l[1] << 16); ul.y = l[2] | (l[3] << 16);
        ul.z = l[4] | (l[5] << 16); ul.w = l[6] | (l[7] << 16);
        *(uint4*)&zTh[(size_t)bb * 512 + k0] = uh;
        *(uint4*)&zTl[(size_t)bb * 512 + k0] = ul;
    } else if (b < 136) {
        int base = (b - 128) * 1024 + tid * 4;
#pragma unroll
        for (int q = 0; q < 4; ++q) {
            int e = base + q, sI = e >> 9, bb = e & 511;
            const float* xp = xenc + ((size_t)bb * SS + sI) * CC;
            int cv = 0;
#pragma unroll
            for (int cc = 0; cc < CC; ++cc) if (xp[cc] > 0.5f) cv = cc;
            cls[sI * BB + bb] = cv;
        }
    } else {
        float4 z4 = make_float4(0.f, 0.f, 0.f, 0.f);
        float4* o4 = (float4*)out;
#pragma unroll
        for (int q = 0; q < 4; ++q)
            o4[(b - 136) * 1024 + q * 256 + tid] = z4;
    }
}

// ---------- MFMA GEMM core: wave = 32 rows x 32 cols x G gates --------------
template<int G>
__device__ __forceinline__ void gemm_core(
    const unsigned short* __restrict__ wf,
    const unsigned short* __restrict__ bTh, const unsigned short* __restrict__ bTl,
    int mt0, int c0, int lane, ffrag* acc)
{
    const char* wp  = (const char*)wf  + (size_t)lane * 16;
    const char* bph = (const char*)bTh + (size_t)(c0 + (lane & 15)) * 1024 + ((lane >> 4) * 16);
    const char* bpl = (const char*)bTl + (size_t)(c0 + (lane & 15)) * 1024 + ((lane >> 4) * 16);
#pragma unroll
    for (int s = 0; s < 16; ++s) {
        bfrag bh[2], bl[2];
#pragma unroll
        for (int n = 0; n < 2; ++n) {
            bh[n] = *(const bfrag*)(bph + n * 16384 + s * 64);
            bl[n] = *(const bfrag*)(bpl + n * 16384 + s * 64);
        }
#pragma unroll
        for (int g = 0; g < G; ++g) {
#pragma unroll
            for (int m = 0; m < 2; ++m) {
                const char* ap = wp + (size_t)((g * 32 + mt0 + m) * 32 + s * 2) * 1024;
                bfrag ah = *(const bfrag*)ap;
                bfrag al = *(const bfrag*)(ap + 1024);
#pragma unroll
                for (int n = 0; n < 2; ++n) {
                    ffrag* A = acc + (g * 2 + m) * 2 + n;
                    *A = __builtin_amdgcn_mfma_f32_16x16x32_bf16(ah, bh[n], *A, 0, 0, 0);
                    *A = __builtin_amdgcn_mfma_f32_16x16x32_bf16(ah, bl[n], *A, 0, 0, 0);
                    *A = __builtin_amdgcn_mfma_f32_16x16x32_bf16(al, bh[n], *A, 0, 0, 0);
                }
            }
        }
    }
}

__device__ __forceinline__ void store_pack(float* __restrict__ dst, int rbase, int c, const float* v) {
    float* p = dst + (size_t)(rbase >> 2) * PBK + c * 4;
    if (rbase + 3 < HH) {
        *(float4*)p = make_float4(v[0], v[1], v[2], v[3]);
    } else {
#pragma unroll
        for (int i = 0; i < 4; ++i) if (rbase + i < HH) p[i] = v[i];
    }
}

__device__ __forceinline__ void store_T(unsigned short* __restrict__ Th, unsigned short* __restrict__ Tl,
                                        int c, int rbase, const float* v) {
    unsigned h[4], l[4];
#pragma unroll
    for (int i = 0; i < 4; ++i) {
        unsigned short hb = f2bf(v[i]);
        h[i] = hb; l[i] = f2bf(v[i] - bf2f(hb));
    }
    uint2 uh, ul;
    uh.x = h[0] | (h[1] << 16); uh.y = h[2] | (h[3] << 16);
    ul.x = l[0] | (l[1] << 16); ul.y = l[2] | (l[3] << 16);
    *(uint2*)&Th[(size_t)c * 512 + rbase] = uh;
    *(uint2*)&Tl[(size_t)c * 512 + rbase] = ul;
}

// ---------- g0 = z @ Wlin1^T + b --------------------------------------------
__global__ __launch_bounds__(128, 1) void k_g0m(
    const unsigned short* __restrict__ zTh, const unsigned short* __restrict__ zTl,
    const unsigned short* __restrict__ wlin, const float* __restrict__ blin1,
    float* __restrict__ dstPack, unsigned short* __restrict__ Th, unsigned short* __restrict__ Tl)
{
    const int tid = threadIdx.x, lane = tid & 63, wv = tid >> 6;
    const int rb = blockIdx.x >> 3, cbb = blockIdx.x & 7;
    const int mt0 = rb * 2, c0 = (cbb * 2 + wv) * 32;
    const ffrag fz = {0.f, 0.f, 0.f, 0.f};
    ffrag acc[4];
#pragma unroll
    for (int i = 0; i < 4; ++i) acc[i] = fz;
    gemm_core<1>(wlin, zTh, zTl, mt0, c0, lane, acc);
#pragma unroll
    for (int m = 0; m < 2; ++m) {
        const int rbase = (mt0 + m) * 16 + ((lane >> 4) << 2);
#pragma unroll
        for (int n = 0; n < 2; ++n) {
            const int c = c0 + n * 16 + (lane & 15);
            float v[4];
#pragma unroll
            for (int r = 0; r < 4; ++r) {
                int rr = rbase + r;
                v[r] = (rr < HH) ? acc[m * 2 + n][r] + blin1[rr] : 0.f;
            }
            store_pack(dstPack, rbase, c, v);
            store_T(Th, Tl, c, rbase, v);
        }
    }
}

// ---------- GRU: h_in -> h --------------------------------------------------
__global__ __launch_bounds__(128, 1) void k_grum(
    const unsigned short* __restrict__ inTh, const unsigned short* __restrict__ inTl,
    const unsigned short* __restrict__ whhf, const float* __restrict__ hinPack,
    const int* __restrict__ cls, const float* __restrict__ Wih,
    const float* __restrict__ bih, const float* __restrict__ bhh,
    int idx, unsigned short* __restrict__ Th, unsigned short* __restrict__ Tl)
{
    const int tid = threadIdx.x, lane = tid & 63, wv = tid >> 6;
    const int rb = blockIdx.x >> 3, cbb = blockIdx.x & 7;
    const int mt0 = rb * 2, c0 = (cbb * 2 + wv) * 32;
    const ffrag fz = {0.f, 0.f, 0.f, 0.f};
    ffrag acc[12];
#pragma unroll
    for (int i = 0; i < 12; ++i) acc[i] = fz;
    gemm_core<3>(whhf, inTh, inTl, mt0, c0, lane, acc);
#pragma unroll
    for (int m = 0; m < 2; ++m) {
        const int rbase = (mt0 + m) * 16 + ((lane >> 4) << 2);
#pragma unroll
        for (int n = 0; n < 2; ++n) {
            const int c = c0 + n * 16 + (lane & 15);
            const int cc = cls[idx * BB + c];
            float hp[4];
            { float4 t = *(const float4*)&hinPack[(size_t)(rbase >> 2) * PBK + c * 4];
              hp[0] = t.x; hp[1] = t.y; hp[2] = t.z; hp[3] = t.w; }
            float v[4];
#pragma unroll
            for (int r = 0; r < 4; ++r) {
                int rr = rbase + r;
                if (rr < HH) {
                    float ar  = acc[(0 * 2 + m) * 2 + n][r];
                    float az  = acc[(1 * 2 + m) * 2 + n][r];
                    float an2 = acc[(2 * 2 + m) * 2 + n][r];
                    float rgt = sigm(Wih[(size_t)rr * CC + cc] + bih[rr] + ar + bhh[rr]);
                    float ugt = sigm(Wih[(size_t)(HH + rr) * CC + cc] + bih[HH + rr] + az + bhh[HH + rr]);
                    float ngt = tanhf(Wih[(size_t)(2 * HH + rr) * CC + cc] + bih[2 * HH + rr]
                                      + rgt * (an2 + bhh[2 * HH + rr]));
                    v[r] = (1.f - ugt) * ngt + ugt * hp[r];
                } else v[r] = 0.f;
            }
            store_T(Th, Tl, c, rbase, v);
        }
    }
}

// ---------- dot role (edge/vertex heads) ------------------------------------
__device__ __forceinline__ void dots_body(
    int blk8, int tid, int lane, int wv,
    const unsigned short* __restrict__ Th, const unsigned short* __restrict__ Tl,
    const unsigned short* __restrict__ wdot, const float* __restrict__ bvert,
    const float* __restrict__ bedge, float* __restrict__ Alist, float* __restrict__ Elist,
    int idx, float* __restrict__ out, float (*dls)[65])
{
    const int c0 = (blk8 * 2 + wv) * 32;
    const ffrag fz = {0.f, 0.f, 0.f, 0.f};
    ffrag acc[2]; acc[0] = fz; acc[1] = fz;
    const char* wp  = (const char*)wdot + (size_t)lane * 16;
    const char* bph = (const char*)Th + (size_t)(c0 + (lane & 15)) * 1024 + ((lane >> 4) * 16);
    const char* bpl = (const char*)Tl + (size_t)(c0 + (lane & 15)) * 1024 + ((lane >> 4) * 16);
#pragma unroll
    for (int s = 0; s < 16; ++s) {
        bfrag ah = *(const bfrag*)(wp + (size_t)(s * 2) * 1024);
        bfrag al = *(const bfrag*)(wp + (size_t)(s * 2 + 1) * 1024);
#pragma unroll
        for (int n = 0; n < 2; ++n) {
            bfrag bh = *(const bfrag*)(bph + n * 16384 + s * 64);
            bfrag bl = *(const bfrag*)(bpl + n * 16384 + s * 64);
            acc[n] = __builtin_amdgcn_mfma_f32_16x16x32_bf16(ah, bh, acc[n], 0, 0, 0);
            acc[n] = __builtin_amdgcn_mfma_f32_16x16x32_bf16(ah, bl, acc[n], 0, 0, 0);
            acc[n] = __builtin_amdgcn_mfma_f32_16x16x32_bf16(al, bh, acc[n], 0, 0, 0);
        }
    }
#pragma unroll
    for (int n = 0; n < 2; ++n)
#pragma unroll
        for (int r = 0; r < 4; ++r)
            dls[((lane >> 4) << 2) + r][wv * 32 + n * 16 + (lane & 15)] = acc[n][r];
    __syncthreads();
    if (tid < 64) {
        const int b = blk8 * 64 + tid;
        float v[9];
#pragma unroll
        for (int j = 0; j < 9; ++j) v[j] = dls[j][tid];
        if (idx >= 0) { Alist[idx * BB + b] = v[0]; Elist[idx * BB + b] = v[1]; }
        if (idx <= SS - 2) {
            float lv[CC], mx = -1e30f;
#pragma unroll
            for (int c = 0; c < CC; ++c) { lv[c] = v[2 + c] + bvert[c]; mx = fmaxf(mx, lv[c]); }
            float sum = 0.f, ev[CC];
#pragma unroll
            for (int c = 0; c < CC; ++c) { ev[c] = expf(lv[c] - mx); sum += ev[c]; }
            float inv = 1.f / sum;
#pragma unroll
            for (int c = 0; c < CC; ++c)
                out[OFF_ENC + ((size_t)b * SS + (idx + 1)) * CC + c] = ev[c] * inv;
        }
        if (idx >= 1) {
            float be = bedge[0];
            float aprev = Alist[(idx - 1) * BB + b], eprev = Elist[(idx - 1) * BB + b];
            out[(size_t)b * SS * SS + idx * SS + (idx - 1)] =
                (aprev + eprev + be >= 0.f) ? 1.f : 0.f;
            for (int vj = 0; vj <= idx - 2; ++vj)
                out[(size_t)b * SS * SS + idx * SS + vj] =
                    (v[0] + Elist[vj * BB + b] + be >= 0.f) ? 1.f : 0.f;
        }
    }
}

__global__ __launch_bounds__(128, 1) void k_dotsm(
    const unsigned short* __restrict__ Th, const unsigned short* __restrict__ Tl,
    const unsigned short* __restrict__ wdot, const float* __restrict__ bvert,
    const float* __restrict__ bedge, float* __restrict__ Alist, float* __restrict__ Elist,
    int idx, float* __restrict__ out)
{
    __shared__ float dls[16][65];
    dots_body(blockIdx.x, threadIdx.x, threadIdx.x & 63, threadIdx.x >> 6,
              Th, Tl, wdot, bvert, bedge, Alist, Elist, idx, out, dls);
}

// ---------- post: h -> next h_in (+ fused dot role blocks) ------------------
__global__ __launch_bounds__(128, 1) void k_postm(
    const unsigned short* __restrict__ hTh, const unsigned short* __restrict__ hTl,
    const unsigned short* __restrict__ wpostf,
    const float* __restrict__ bgate, const float* __restrict__ bmap,
    const float* __restrict__ dep,
    const unsigned short* __restrict__ wdot, const float* __restrict__ bvert,
    const float* __restrict__ bedge, float* __restrict__ Alist, float* __restrict__ Elist,
    int idx, float* __restrict__ dstPack,
    unsigned short* __restrict__ Th, unsigned short* __restrict__ Tl,
    float* __restrict__ out)
{
    __shared__ float dls[16][65];
    const int tid = threadIdx.x, lane = tid & 63, wv = tid >> 6;
    if ((int)blockIdx.x < 128) {
        const int rb = blockIdx.x >> 3, cbb = blockIdx.x & 7;
        const int mt0 = rb * 2, c0 = (cbb * 2 + wv) * 32;
        const ffrag fz = {0.f, 0.f, 0.f, 0.f};
        ffrag acc[8];
#pragma unroll
        for (int i = 0; i < 8; ++i) acc[i] = fz;
        gemm_core<2>(wpostf, hTh, hTl, mt0, c0, lane, acc);
#pragma unroll
        for (int m = 0; m < 2; ++m) {
            const int rbase = (mt0 + m) * 16 + ((lane >> 4) << 2);
#pragma unroll
            for (int n = 0; n < 2; ++n) {
                const int c = c0 + n * 16 + (lane & 15);
                const float d = dep[(size_t)c * (SS * SS) + (idx + 1) * SS + idx];
                float v[4];
#pragma unroll
                for (int r = 0; r < 4; ++r) {
                    int rr = rbase + r;
                    if (rr < HH) {
                        float bg = bgate[rr], bm = bmap[rr];
                        float cv = sigm(bg) * bm;
                        float f = sigm(acc[(0 * 2 + m) * 2 + n][r] + bg)
                                * (acc[(1 * 2 + m) * 2 + n][r] + bm);
                        v[r] = (d != 0.f) ? (f + 15.f * cv) : (16.f * cv);
                    } else v[r] = 0.f;
                }
                store_pack(dstPack, rbase, c, v);
                store_T(Th, Tl, c, rbase, v);
            }
        }
    } else {
        dots_body((int)blockIdx.x - 128, tid, lane, wv,
                  hTh, hTl, wdot, bvert, bedge, Alist, Elist, idx, out, dls);
    }
}

extern "C" void kernel_launch(void* const* d_in, const int* in_sizes, int n_in,
                              void* d_out, int out_size, void* d_ws, size_t ws_size,
                              hipStream_t stream)
{
    const float* z     = (const float*)d_in[0];
    const float* dep   = (const float*)d_in[1];
    const float* xenc  = (const float*)d_in[2];
    const float* Wlin1 = (const float*)d_in[3];
    const float* blin1 = (const float*)d_in[4];
    const float* Wvert = (const float*)d_in[5];
    const float* bvert = (const float*)d_in[6];
    const float* Wedge = (const float*)d_in[7];
    const float* bedge = (const float*)d_in[8];
    const float* Wgate = (const float*)d_in[9];
    const float* bgate = (const float*)d_in[10];
    const float* Wmap  = (const float*)d_in[11];
    const float* bmap  = (const float*)d_in[12];
    const float* Wih   = (const float*)d_in[13];
    const float* bih   = (const float*)d_in[14];
    const float* Whh   = (const float*)d_in[15];
    const float* bhh   = (const float*)d_in[16];
    float* out = (float*)d_out;

    float* ws    = (float*)d_ws;
    float* bufIn = ws + O_BUFIN;
    float* Alist = ws + O_ALIST;
    float* Elist = ws + O_ELIST;
    int*   cls   = (int*)(ws + O_CLS);
    unsigned short* zTh  = (unsigned short*)(ws + O_ZT);
    unsigned short* zTl  = zTh + 262144;
    unsigned short* inTh = (unsigned short*)(ws + O_INT);
    unsigned short* inTl = inTh + 262144;
    unsigned short* hTh  = (unsigned short*)(ws + O_HT);
    unsigned short* hTl  = hTh + 262144;
    unsigned short* wlin  = (unsigned short*)(ws + O_WLIN);
    unsigned short* wpost = (unsigned short*)(ws + O_WPOST);
    unsigned short* whhf  = (unsigned short*)(ws + O_WHH);
    unsigned short* wdot  = (unsigned short*)(ws + O_WDOT);

    k_wprep<<<772, 256, 0, stream>>>(Wlin1, Wgate, Wmap, Whh, Wedge, Wvert,
                                     wlin, wpost, whhf, wdot);
    k_prep2<<<168, 256, 0, stream>>>(z, xenc, zTh, zTl, cls, out);
    k_g0m<<<128, 128, 0, stream>>>(zTh, zTl, wlin, blin1, bufIn, inTh, inTl);
    k_dotsm<<<8, 128, 0, stream>>>(inTh, inTl, wdot, bvert, bedge, Alist, Elist, -1, out);
    for (int idx = 0; idx < SS; ++idx) {
        k_grum<<<128, 128, 0, stream>>>(inTh, inTl, whhf, bufIn, cls, Wih, bih, bhh,
                                        idx, hTh, hTl);
        if (idx < SS - 1)
            k_postm<<<136, 128, 0, stream>>>(hTh, hTl, wpost, bgate, bmap, dep,
                                             wdot, bvert, bedge, Alist, Elist,
                                             idx, bufIn, inTh, inTl, out);
        else
            k_dotsm<<<8, 128, 0, stream>>>(hTh, hTl, wdot, bvert, bedge, Alist, Elist,
                                           idx, out);
    }
}